// Round 13
// baseline (376.523 us; speedup 1.0000x reference)
//
#include <hip/hip_runtime.h>

#define NB 2
#define CCH 64
#define LL 8
#define HH 160
#define WW 160
#define PP 8
#define NPH 20
#define NPW 20
#define NPAT 800
#define NE 8
#define HWX 25600
#define CSTRIDE 204800

typedef float f32x4  __attribute__((ext_vector_type(4)));
typedef float f32x16 __attribute__((ext_vector_type(16)));
typedef short bf16x8 __attribute__((ext_vector_type(8)));

__device__ __host__ __forceinline__ unsigned short f2bf(float f) {
    unsigned u = __builtin_bit_cast(unsigned, f);
    u = (u + 0x7FFFu + ((u >> 16) & 1u)) >> 16;
    return (unsigned short)u;
}
__device__ __forceinline__ unsigned cvtpk(float lo, float hi) {
    unsigned r;
    asm("v_cvt_pk_bf16_f32 %0, %1, %2" : "=v"(r) : "v"(lo), "v"(hi));
    return r;
}
__device__ __forceinline__ float dpp_xor1(float v) {  // quad_perm [1,0,3,2]
    int s = __builtin_bit_cast(int, v);
    return __builtin_bit_cast(float, __builtin_amdgcn_update_dpp(s, s, 0xB1, 0xF, 0xF, false));
}
__device__ __forceinline__ int xsw(int s) { return ((s & 7) ^ ((s >> 3) & 7)) << 2; }

// ---------------- Prep: w1t (interleaved a/g rows), w2t, paired block-diagonal conv table ----
__global__ __launch_bounds__(256)
void prep_kernel(const float* __restrict__ pwin_w, const float* __restrict__ pwout_w,
                 const float* __restrict__ dw_w,
                 unsigned short* __restrict__ w1t, unsigned short* __restrict__ w2t,
                 unsigned short* __restrict__ tbl, unsigned* __restrict__ zp, int full)
{
    int idx = blockIdx.x * 256 + threadIdx.x;    // grid 2048 -> 524288
    {
        int j = idx & 7, lane = (idx >> 3) & 63, ks2 = (idx >> 9) & 3;
        int po = (idx >> 11) & 31, e = (idx >> 16) & 7;
        int m16 = lane & 15;
        int ch = m16 >> 3, jout = m16 & 7;
        int k128 = ks2*32 + ((lane >> 4) << 3) + j;
        int kc = k128 >> 6, k64 = k128 & 63;
        int di = k64 >> 3, jj = k64 & 7;
        int dj = jj - jout + 3;
        int h = po >> 4, mm = po & 15;
        int c = 32*h + mm + ch*16;
        float v = 0.f;
        if (kc == ch && di < 7 && dj >= 0 && dj < 7)
            v = dw_w[(e*CCH + c)*49 + di*7 + dj];
        tbl[idx] = f2bf(v);
    }
    if (idx < NE*128*64) {
        int e = idx >> 13, r = (idx >> 6) & 127, c = idx & 63;
        int orig = (r & 1) ? 64 + (r >> 1) : (r >> 1);
        w1t[idx] = f2bf(pwin_w[(e << 13) + orig*64 + c]);
    }
    if (idx < NE*64*64) w2t[idx] = f2bf(pwout_w[idx]);
    if (full && idx < 16) zp[idx] = 0u;
}

// ---------------- Router stage 1: partial sums + (optional) xbf conversion ----------------
// xbf tile T=((b*20+ph)*10+pwq)*4+lp : [c][l2][row][p][j] bf16, 16384 ushorts/tile
__global__ __launch_bounds__(256)
void router_sum(const float* __restrict__ x, float* __restrict__ pmean2,
                unsigned short* __restrict__ xbf, int do_xbf)
{
    int bid = blockIdx.x;                        // 320 = b(2) x l(8) x ph(20)
    int ph = bid % 20;
    int r  = bid / 20;
    int l  = r % 8;
    int b  = r / 8;
    int lp = l >> 1, l2 = l & 1;

    __shared__ float acc[1280];
    const float* base = x + ((size_t)(b*CCH)*LL + l)*HWX + (size_t)(ph*PP)*WW;
    int t = threadIdx.x;

    #pragma unroll
    for (int k = 0; k < 5; ++k) {
        int s = t + 256*k;
        int pw = s % 20, c = s / 20;
        const float* rp = base + (size_t)c*CSTRIDE + pw*8;
        int pwq = pw >> 1, pp2 = pw & 1;
        size_t tb = ((((size_t)(b*20 + ph))*10 + pwq)*4 + lp)*16384
                    + (size_t)c*256 + l2*128 + pp2*8;
        float sum = 0.f;
        #pragma unroll
        for (int i = 0; i < 8; ++i) {
            float4 v0 = *(const float4*)(rp + i*WW);
            float4 v1 = *(const float4*)(rp + i*WW + 4);
            sum += v0.x+v0.y+v0.z+v0.w + v1.x+v1.y+v1.z+v1.w;
            if (do_xbf) {
                uint4 wv;
                wv.x = cvtpk(v0.x, v0.y);
                wv.y = cvtpk(v0.z, v0.w);
                wv.z = cvtpk(v1.x, v1.y);
                wv.w = cvtpk(v1.z, v1.w);
                *(uint4*)(xbf + tb + i*16) = wv;
            }
        }
        acc[c*20 + pw] = sum;
    }
    __syncthreads();
    #pragma unroll
    for (int k = 0; k < 5; ++k) {
        int s = t + 256*k;
        int c = s & 63, pwi = s >> 6;
        int n = b*400 + ph*20 + pwi;
        pmean2[(size_t)n*512 + l*64 + c] = acc[c*20 + pwi];
    }
}

// ---------------- Router stage 2: logits + top-2 softmax ----------------
__global__ __launch_bounds__(64)
void router_top(const float* __restrict__ pmean2,
                const float* __restrict__ rw, const float* __restrict__ rb,
                int* __restrict__ sel_idx, float* __restrict__ sel_w)
{
    int n = blockIdx.x;
    int t = threadIdx.x;
    __shared__ float mc[64];
    __shared__ float lg[8];
    const float* pb = pmean2 + (size_t)n*512;
    float s = 0.f;
    #pragma unroll
    for (int l = 0; l < 8; ++l) s += pb[l*64 + t];
    mc[t] = s * (1.f/512.f);
    __syncthreads();
    if (t < 8) {
        float a = rb[t];
        for (int c = 0; c < 64; ++c) a += mc[c] * rw[t*64 + c];
        lg[t] = a;
    }
    __syncthreads();
    if (t == 0) {
        float m0 = -1e30f; int i0 = 0;
        #pragma unroll
        for (int e = 0; e < NE; ++e) { float v = lg[e]; if (v > m0) { m0 = v; i0 = e; } }
        float m1 = -1e30f; int i1 = 0;
        #pragma unroll
        for (int e = 0; e < NE; ++e) { if (e != i0) { float v = lg[e]; if (v > m1) { m1 = v; i1 = e; } } }
        float dd = __expf(m1 - m0);
        float inv = 1.f / (1.f + dd);
        sel_idx[n*2]   = i0;  sel_idx[n*2+1] = i1;
        sel_w[n*2]     = inv; sel_w[n*2+1]   = dd * inv;
    }
}

// ---------------- Main v13: conv B from global xbf; LDS = 4 Y slices (~32 KB) ----------------
__global__ __launch_bounds__(256, 3)
void moe_v13(const float* __restrict__ x,
             const float* __restrict__ ln_g,
             const float* __restrict__ ln_b,
             const float* __restrict__ pwin_b,
             const float* __restrict__ pwout_b,
             const unsigned short* __restrict__ w1t,
             const unsigned short* __restrict__ w2t,
             const unsigned short* __restrict__ tbl,
             const unsigned short* __restrict__ xbf,
             const unsigned short* __restrict__ zp,
             const int* __restrict__ sel_idx,
             const float* __restrict__ sel_w,
             float* __restrict__ out)
{
    __shared__ __align__(16) unsigned smem[8224];    // 4 slices x 2056 dwords
    float* obuf = (float*)smem;                      // epilogue reuse [0,8192)

    int bid = blockIdx.x;
    int xg = bid & 7, pp = (bid >> 3) & 1, w = bid >> 4;
    int b = xg >> 2, lp = xg & 3;
    int ph = w / 5, pwh = w - ph*5;
    int pwq = pwh*2 + pp;

    int t = threadIdx.x;
    int lane = t & 63;
    int wv = __builtin_amdgcn_readfirstlane(t >> 6);
    int p = wv & 1;
    int h = wv >> 1;
    int col16 = lane & 15, grp = lane >> 4;
    int io = col16 & 7, l2n = col16 >> 3;
    int laneM = lane & 31, hi = lane >> 5;
    bool oddl = (lane & 1) != 0;
    int srow_b = (oddl ? 32 : 0) + 4*hi;
    int sx = (h & 1) << 2;

    size_t xpb = ((size_t)(b*CCH)*LL + lp*2)*HWX + (size_t)(ph*PP)*WW + pwq*16;
    int np = b*400 + ph*20 + pwq*2 + p;
    int Tidx = ((b*20 + ph)*10 + pwq)*4 + lp;
    const unsigned short* xt = xbf + (size_t)Tidx*16384;

    int e0 = __builtin_amdgcn_readfirstlane(sel_idx[np*2]);
    int e1 = __builtin_amdgcn_readfirstlane(sel_idx[np*2+1]);
    float wA = sel_w[np*2], wB = sel_w[np*2+1];

    f32x16 oacc[2][2];
    #pragma unroll
    for (int st = 0; st < 2; ++st)
        #pragma unroll
        for (int ct = 0; ct < 2; ++ct)
            #pragma unroll
            for (int i = 0; i < 16; ++i) oacc[st][ct][i] = 0.f;

    unsigned* sl = smem + (p*2 + h)*2056;

    int loff[2]; bool okr[2];
    #pragma unroll
    for (int ks = 0; ks < 2; ++ks) {
        int row = io + ks*4 + grp - 3;
        loff[ks] = l2n*128 + (row & 7)*16 + p*8;
        okr[ks] = (unsigned)row < 8u;
    }
    int sb = io*8 + (grp & 1)*4;
    int chs = grp >> 1;
    int sp2 = p*2 + l2n;
    int csx = l2n << 2;

    #pragma unroll 1
    for (int pass = 0; pass < 2; ++pass) {
        int e    = pass ? e1 : e0;
        float we = pass ? wB : wA;

        // ---- conv: paired block-diagonal MFMA (B from global xbf) + per-channel LN ----
        const unsigned short* te = tbl + (((size_t)(e*32 + h*16)) << 11);
        float gv[4], bv[4];
        #pragma unroll
        for (int r = 0; r < 4; ++r) {
            gv[r] = ln_g[e*64 + sb + r];
            bv[r] = ln_b[e*64 + sb + r];
        }

        #pragma unroll 2
        for (int m = 0; m < 16; ++m) {
            int cA = 32*h + m;
            const unsigned short* tm = te + ((size_t)m << 11);
            f32x4 ac; ac[0]=0.f; ac[1]=0.f; ac[2]=0.f; ac[3]=0.f;
            #pragma unroll
            for (int ks2 = 0; ks2 < 4; ++ks2) {
                int cc = cA + ((ks2 & 2) ? 16 : 0);
                int ks = ks2 & 1;
                const unsigned short* bp = okr[ks] ? (xt + cc*256 + loff[ks]) : zp;
                uint4 bu = *(const uint4*)bp;
                uint4 af = *(const uint4*)(tm + ks2*512 + lane*8);
                ac = __builtin_amdgcn_mfma_f32_16x16x32_bf16(
                    __builtin_bit_cast(bf16x8, af), __builtin_bit_cast(bf16x8, bu), ac, 0, 0, 0);
            }
            float sum = ac[0]+ac[1]+ac[2]+ac[3];
            float sq  = 0.f;
            #pragma unroll
            for (int r = 0; r < 4; ++r) sq = fmaf(ac[r], ac[r], sq);
            sum += __shfl_xor(sum, 1);  sq += __shfl_xor(sq, 1);
            sum += __shfl_xor(sum, 2);  sq += __shfl_xor(sq, 2);
            sum += __shfl_xor(sum, 4);  sq += __shfl_xor(sq, 4);
            sum += __shfl_xor(sum, 16); sq += __shfl_xor(sq, 16);
            float mu  = sum * 0.015625f;
            float var = fmaxf(fmaf(sq, 0.015625f, -mu*mu), 0.f);
            float inv = rsqrtf(var + 1e-5f);
            float nmu = -mu * inv;
            int myc = cA + (chs ? 16 : 0);
            unsigned short* Yh = (unsigned short*)smem;
            int cd = (myc >> 1), cb = myc & 1;
            #pragma unroll
            for (int r = 0; r < 4; ++r) {
                float y = fmaf(fmaf(ac[r], inv, nmu), gv[r], bv[r]);
                int s = sb + r;
                int dw = sp2*2056 + s*32 + ((cd ^ xsw(s)) ^ csx);
                Yh[dw*2 + cb] = (unsigned short)cvtpk(y, y);
            }
        }
        __syncthreads();                             // B2: all Y slices complete

        // ---- solo GEMMs on private slice ----
        uint4 aY0[4], aY1[4];
        #pragma unroll
        for (int ks = 0; ks < 4; ++ks) {
            int kd = 8*ks + 4*hi;
            aY0[ks] = *(const uint4*)&sl[laneM*32 + ((kd ^ xsw(laneM)) ^ sx)];
            aY1[ks] = *(const uint4*)&sl[(32 + laneM)*32 + ((kd ^ xsw(32 + laneM)) ^ sx)];
        }
        const unsigned short* w1e = w1t + ((size_t)e << 13);
        const unsigned short* w2e = w2t + ((size_t)e << 12);

        #pragma unroll 1
        for (int dt = 0; dt < 4; ++dt) {
            uint4 b1f[4];
            #pragma unroll
            for (int ks = 0; ks < 4; ++ks)
                b1f[ks] = *(const uint4*)(w1e + (32*dt + laneM)*64 + 16*ks + 8*hi);
            int dp = 32*dt + laneM;
            int borig = (dp & 1) ? 64 + (dp >> 1) : (dp >> 1);
            float bias1 = pwin_b[e*128 + borig];

            f32x16 acc0, acc1;
            #pragma unroll
            for (int i = 0; i < 16; ++i) { acc0[i]=0.f; acc1[i]=0.f; }
            #pragma unroll
            for (int ks = 0; ks < 4; ++ks) {
                bf16x8 bvf = __builtin_bit_cast(bf16x8, b1f[ks]);
                acc0 = __builtin_amdgcn_mfma_f32_32x32x16_bf16(
                    __builtin_bit_cast(bf16x8, aY0[ks]), bvf, acc0, 0, 0, 0);
                acc1 = __builtin_amdgcn_mfma_f32_32x32x16_bf16(
                    __builtin_bit_cast(bf16x8, aY1[ks]), bvf, acc1, 0, 0, 0);
            }
            int kg  = 16*dt + (laneM >> 1);
            int kdg = kg >> 1, kbit = kg & 1;
            #pragma unroll
            for (int r = 0; r < 16; ++r) {
                float h0 = acc0[r] + bias1;
                float h1 = acc1[r] + bias1;
                float p0 = dpp_xor1(h0);
                float p1 = dpp_xor1(h1);
                float A = oddl ? p1 : h0;
                float G = oddl ? h1 : p0;
                float sg = __builtin_amdgcn_rcpf(1.f + __expf(-A));
                float val = A * sg * G;
                int srow = srow_b + (r & 3) + 8*(r >> 2);
                int dwg = srow*32 + ((kdg ^ xsw(srow)) ^ sx);
                ((unsigned short*)sl)[dwg*2 + kbit] = (unsigned short)cvtpk(val, val);
            }
        }
        // ---- GEMM2 ----
        #pragma unroll
        for (int ct = 0; ct < 2; ++ct) {
            int cn = 32*ct + laneM;
            uint4 b2f[4];
            #pragma unroll
            for (int ks = 0; ks < 4; ++ks)
                b2f[ks] = *(const uint4*)(w2e + cn*64 + 16*ks + 8*hi);
            float bias2 = pwout_b[e*64 + cn];
            #pragma unroll
            for (int st = 0; st < 2; ++st) {
                f32x16 g;
                #pragma unroll
                for (int i = 0; i < 16; ++i) g[i] = 0.f;
                #pragma unroll
                for (int ks = 0; ks < 4; ++ks) {
                    int sG = 32*st + laneM;
                    int kd = 8*ks + 4*hi;
                    uint4 ag = *(const uint4*)&sl[sG*32 + ((kd ^ xsw(sG)) ^ sx)];
                    g = __builtin_amdgcn_mfma_f32_32x32x16_bf16(
                        __builtin_bit_cast(bf16x8, ag), __builtin_bit_cast(bf16x8, b2f[ks]), g, 0, 0, 0);
                }
                #pragma unroll
                for (int i = 0; i < 16; ++i)
                    oacc[st][ct][i] = fmaf(we, g[i] + bias2, oacc[st][ct][i]);
            }
        }
        __syncthreads();                             // B3: slice reads done
    }

    // ---- epilogue: 2 phases (l2 = 0,1), 32 KB obuf per phase, float4 global I/O ----
    #pragma unroll 1
    for (int ph2 = 0; ph2 < 2; ++ph2) {
        if (h == ph2) {
            float* obr = obuf + p*4096;
            #pragma unroll
            for (int st = 0; st < 2; ++st)
                #pragma unroll
                for (int ct = 0; ct < 2; ++ct)
                    #pragma unroll
                    for (int r = 0; r < 16; ++r) {
                        int c = 32*ct + laneM;
                        int s = 32*st + 4*hi + (r & 3) + 8*(r >> 2);
                        obr[c*64 + (s ^ c)] = oacc[st][ct][r];
                    }
        }
        __syncthreads();
        #pragma unroll
        for (int rr = 0; rr < 8; ++rr) {
            int row = rr*64 + (t >> 2);              // 0..511 = (c, i)
            int c = row >> 3, i = row & 7;
            int q4 = (t & 3) * 4;
            int pq = q4 >> 3;
            int jb = q4 & 7;
            int ob = pq*4096 + c*64;
            float4 v;
            v.x = obuf[ob + ((i*8 + jb + 0) ^ c)];
            v.y = obuf[ob + ((i*8 + jb + 1) ^ c)];
            v.z = obuf[ob + ((i*8 + jb + 2) ^ c)];
            v.w = obuf[ob + ((i*8 + jb + 3) ^ c)];
            size_t ga = xpb + (size_t)c*CSTRIDE + (size_t)ph2*HWX + i*WW + q4;
            float4 xr = *(const float4*)(x + ga);
            v.x += xr.x; v.y += xr.y; v.z += xr.z; v.w += xr.w;
            *(float4*)(out + ga) = v;
        }
        if (ph2 == 0) __syncthreads();
    }
}

// ---------------- Fallback: verified v12 kernel (LDS xs staging) ----------------
__global__ __launch_bounds__(256, 2)
void moe_v12(const float* __restrict__ x,
             const float* __restrict__ ln_g,
             const float* __restrict__ ln_b,
             const float* __restrict__ pwin_b,
             const float* __restrict__ pwout_b,
             const unsigned short* __restrict__ w1t,
             const unsigned short* __restrict__ w2t,
             const unsigned short* __restrict__ tbl,
             const int* __restrict__ sel_idx,
             const float* __restrict__ sel_w,
             float* __restrict__ out)
{
    __shared__ __align__(16) unsigned smem[16400];
    unsigned* xs = smem;
    float* obuf  = (float*)smem;

    int bid = blockIdx.x;
    int xg = bid & 7, pp = (bid >> 3) & 1, w = bid >> 4;
    int b = xg >> 2, lp = xg & 3;
    int ph = w / 5, pwh = w - ph*5;
    int pwq = pwh*2 + pp;

    int t = threadIdx.x;
    int lane = t & 63;
    int wv = __builtin_amdgcn_readfirstlane(t >> 6);
    int p = wv & 1;
    int h = wv >> 1;
    int col16 = lane & 15, grp = lane >> 4;
    int io = col16 & 7, l2n = col16 >> 3;
    int laneM = lane & 31, hi = lane >> 5;
    bool oddl = (lane & 1) != 0;
    int srow_b = (oddl ? 32 : 0) + 4*hi;
    int sx = (h & 1) << 2;

    size_t xpb = ((size_t)(b*CCH)*LL + lp*2)*HWX + (size_t)(ph*PP)*WW + pwq*16;
    int np = b*400 + ph*20 + pwq*2 + p;

    if (t < 16) smem[16384 + t] = 0u;

    #pragma unroll
    for (int k = 0; k < 16; ++k) {
        int id = t + 256*k;
        int part = id & 3, i = (id >> 2) & 7, l2s = (id >> 5) & 1, c = id >> 6;
        const float* rp = x + xpb + (size_t)c*CSTRIDE + (size_t)l2s*HWX + i*WW + part*4;
        float4 v = *(const float4*)rp;
        uint2 bu;
        bu.x = cvtpk(v.x, v.y);
        bu.y = cvtpk(v.z, v.w);
        int off = (part*2) ^ (((l2s ^ (i >> 2)) & 1) << 2);
        *(uint2*)&xs[c*128 + l2s*64 + i*8 + off] = bu;
    }
    __syncthreads();

    int e0 = __builtin_amdgcn_readfirstlane(sel_idx[np*2]);
    int e1 = __builtin_amdgcn_readfirstlane(sel_idx[np*2+1]);
    float wA = sel_w[np*2], wB = sel_w[np*2+1];

    f32x16 oacc[2][2];
    #pragma unroll
    for (int st = 0; st < 2; ++st)
        #pragma unroll
        for (int ct = 0; ct < 2; ++ct)
            #pragma unroll
            for (int i = 0; i < 16; ++i) oacc[st][ct][i] = 0.f;

    unsigned* sl = smem + 8192 + (p*2 + h)*2048;

    int rowoff[2]; bool okr[2];
    #pragma unroll
    for (int ks = 0; ks < 2; ++ks) {
        int row = io + ks*4 + grp - 3;
        int rw = row & 7;
        rowoff[ks] = l2n*64 + rw*8 + (((p ^ l2n ^ (rw >> 2)) & 1) << 2);
        okr[ks] = (unsigned)row < 8u;
    }
    int sb = io*8 + (grp & 1)*4;
    int chs = grp >> 1;
    int sp2 = p*2 + l2n;
    int csx = l2n << 2;

    #pragma unroll 1
    for (int pass = 0; pass < 2; ++pass) {
        int e    = pass ? e1 : e0;
        float we = pass ? wB : wA;

        const unsigned short* te = tbl + (((size_t)(e*32 + h*16)) << 11);
        float gv[4], bv[4];
        #pragma unroll
        for (int r = 0; r < 4; ++r) {
            gv[r] = ln_g[e*64 + sb + r];
            bv[r] = ln_b[e*64 + sb + r];
        }

        #pragma unroll 2
        for (int m = 0; m < 16; ++m) {
            int cA = 32*h + m;
            const unsigned short* tm = te + ((size_t)m << 11);
            f32x4 ac; ac[0]=0.f; ac[1]=0.f; ac[2]=0.f; ac[3]=0.f;
            #pragma unroll
            for (int ks2 = 0; ks2 < 4; ++ks2) {
                int c = cA + ((ks2 & 2) ? 16 : 0);
                int ks = ks2 & 1;
                int aB = okr[ks] ? (c*128 + rowoff[ks]) : 16384;
                uint4 bu = *(const uint4*)&xs[aB];
                uint4 af = *(const uint4*)(tm + ks2*512 + lane*8);
                ac = __builtin_amdgcn_mfma_f32_16x16x32_bf16(
                    __builtin_bit_cast(bf16x8, af), __builtin_bit_cast(bf16x8, bu), ac, 0, 0, 0);
            }
            float sum = ac[0]+ac[1]+ac[2]+ac[3];
            float sq  = 0.f;
            #pragma unroll
            for (int r = 0; r < 4; ++r) sq = fmaf(ac[r], ac[r], sq);
            sum += __shfl_xor(sum, 1);  sq += __shfl_xor(sq, 1);
            sum += __shfl_xor(sum, 2);  sq += __shfl_xor(sq, 2);
            sum += __shfl_xor(sum, 4);  sq += __shfl_xor(sq, 4);
            sum += __shfl_xor(sum, 16); sq += __shfl_xor(sq, 16);
            float mu  = sum * 0.015625f;
            float var = fmaxf(fmaf(sq, 0.015625f, -mu*mu), 0.f);
            float inv = rsqrtf(var + 1e-5f);
            float nmu = -mu * inv;
            int myc = cA + (chs ? 16 : 0);
            unsigned short* Yh = (unsigned short*)smem;
            int cd = (myc >> 1), cb = myc & 1;
            #pragma unroll
            for (int r = 0; r < 4; ++r) {
                float y = fmaf(fmaf(ac[r], inv, nmu), gv[r], bv[r]);
                int s = sb + r;
                int dw = 8192 + sp2*2048 + s*32 + ((cd ^ xsw(s)) ^ csx);
                Yh[dw*2 + cb] = (unsigned short)cvtpk(y, y);
            }
        }
        __syncthreads();

        uint4 aY0[4], aY1[4];
        #pragma unroll
        for (int ks = 0; ks < 4; ++ks) {
            int kd = 8*ks + 4*hi;
            aY0[ks] = *(const uint4*)&sl[laneM*32 + ((kd ^ xsw(laneM)) ^ sx)];
            aY1[ks] = *(const uint4*)&sl[(32 + laneM)*32 + ((kd ^ xsw(32 + laneM)) ^ sx)];
        }
        const unsigned short* w1e = w1t + ((size_t)e << 13);
        const unsigned short* w2e = w2t + ((size_t)e << 12);

        #pragma unroll 1
        for (int dt = 0; dt < 4; ++dt) {
            uint4 b1f[4];
            #pragma unroll
            for (int ks = 0; ks < 4; ++ks)
                b1f[ks] = *(const uint4*)(w1e + (32*dt + laneM)*64 + 16*ks + 8*hi);
            int dp = 32*dt + laneM;
            int borig = (dp & 1) ? 64 + (dp >> 1) : (dp >> 1);
            float bias1 = pwin_b[e*128 + borig];

            f32x16 acc0, acc1;
            #pragma unroll
            for (int i = 0; i < 16; ++i) { acc0[i]=0.f; acc1[i]=0.f; }
            #pragma unroll
            for (int ks = 0; ks < 4; ++ks) {
                bf16x8 bvf = __builtin_bit_cast(bf16x8, b1f[ks]);
                acc0 = __builtin_amdgcn_mfma_f32_32x32x16_bf16(
                    __builtin_bit_cast(bf16x8, aY0[ks]), bvf, acc0, 0, 0, 0);
                acc1 = __builtin_amdgcn_mfma_f32_32x32x16_bf16(
                    __builtin_bit_cast(bf16x8, aY1[ks]), bvf, acc1, 0, 0, 0);
            }
            int kg  = 16*dt + (laneM >> 1);
            int kdg = kg >> 1, kbit = kg & 1;
            #pragma unroll
            for (int r = 0; r < 16; ++r) {
                float h0 = acc0[r] + bias1;
                float h1 = acc1[r] + bias1;
                float p0 = dpp_xor1(h0);
                float p1 = dpp_xor1(h1);
                float A = oddl ? p1 : h0;
                float G = oddl ? h1 : p0;
                float sg = __builtin_amdgcn_rcpf(1.f + __expf(-A));
                float val = A * sg * G;
                int srow = srow_b + (r & 3) + 8*(r >> 2);
                int dwg = srow*32 + ((kdg ^ xsw(srow)) ^ sx);
                ((unsigned short*)sl)[dwg*2 + kbit] = (unsigned short)cvtpk(val, val);
            }
        }
        #pragma unroll
        for (int ct = 0; ct < 2; ++ct) {
            int cn = 32*ct + laneM;
            uint4 b2f[4];
            #pragma unroll
            for (int ks = 0; ks < 4; ++ks)
                b2f[ks] = *(const uint4*)(w2e + cn*64 + 16*ks + 8*hi);
            float bias2 = pwout_b[e*64 + cn];
            #pragma unroll
            for (int st = 0; st < 2; ++st) {
                f32x16 g;
                #pragma unroll
                for (int i = 0; i < 16; ++i) g[i] = 0.f;
                #pragma unroll
                for (int ks = 0; ks < 4; ++ks) {
                    int sG = 32*st + laneM;
                    int kd = 8*ks + 4*hi;
                    uint4 ag = *(const uint4*)&sl[sG*32 + ((kd ^ xsw(sG)) ^ sx)];
                    g = __builtin_amdgcn_mfma_f32_32x32x16_bf16(
                        __builtin_bit_cast(bf16x8, ag), __builtin_bit_cast(bf16x8, b2f[ks]), g, 0, 0, 0);
                }
                #pragma unroll
                for (int i = 0; i < 16; ++i)
                    oacc[st][ct][i] = fmaf(we, g[i] + bias2, oacc[st][ct][i]);
            }
        }
        __syncthreads();
    }

    {
        float* obr = obuf + (p*2 + h)*4096;
        #pragma unroll
        for (int st = 0; st < 2; ++st)
            #pragma unroll
            for (int ct = 0; ct < 2; ++ct)
                #pragma unroll
                for (int r = 0; r < 16; ++r) {
                    int c = 32*ct + laneM;
                    int s = 32*st + 4*hi + (r & 3) + 8*(r >> 2);
                    obr[c*64 + (s ^ c)] = oacc[st][ct][r];
                }
        __syncthreads();
        #pragma unroll
        for (int rr = 0; rr < 16; ++rr) {
            int row = rr*64 + (t >> 2);
            int l2s = row >> 9;
            int rem = row & 511;
            int c = rem >> 3, i = rem & 7;
            int q4 = (t & 3) * 4;
            int pq = q4 >> 3;
            int jb = q4 & 7;
            int ob = (pq*2 + l2s)*4096 + c*64;
            float4 v;
            v.x = obuf[ob + ((i*8 + jb + 0) ^ c)];
            v.y = obuf[ob + ((i*8 + jb + 1) ^ c)];
            v.z = obuf[ob + ((i*8 + jb + 2) ^ c)];
            v.w = obuf[ob + ((i*8 + jb + 3) ^ c)];
            size_t ga = xpb + (size_t)c*CSTRIDE + (size_t)l2s*HWX + i*WW + q4;
            float4 xr = *(const float4*)(x + ga);
            v.x += xr.x; v.y += xr.y; v.z += xr.z; v.w += xr.w;
            *(float4*)(out + ga) = v;
        }
    }
}

extern "C" void kernel_launch(void* const* d_in, const int* in_sizes, int n_in,
                              void* d_out, int out_size, void* d_ws, size_t ws_size,
                              hipStream_t stream) {
    const float* x        = (const float*)d_in[0];
    const float* router_w = (const float*)d_in[1];
    const float* router_b = (const float*)d_in[2];
    const float* dw_w     = (const float*)d_in[3];
    const float* ln_g     = (const float*)d_in[5];
    const float* ln_b     = (const float*)d_in[6];
    const float* pwin_w   = (const float*)d_in[7];
    const float* pwin_b   = (const float*)d_in[8];
    const float* pwout_w  = (const float*)d_in[9];
    const float* pwout_b  = (const float*)d_in[10];
    float* out = (float*)d_out;

    char* ws = (char*)d_ws;
    int*            sel_idx = (int*)ws;                        // [0, 6400)
    float*          sel_w   = (float*)(ws + 6400);             // [6400, 12800)
    unsigned short* w1t     = (unsigned short*)(ws + 12800);   // 131072 B
    unsigned short* w2t     = (unsigned short*)(ws + 143872);  // 65536 B
    unsigned short* tbl     = (unsigned short*)(ws + 209408);  // 1048576 B -> 1257984
    float*          pmean2  = (float*)(ws + 1257984);          // 1638400 B -> 2896384
    unsigned*       zp      = (unsigned*)(ws + 2896384);       // 64 B -> 2896448
    unsigned short* xbf     = (unsigned short*)(ws + 2896448); // 52428800 B -> 55325248

    const size_t NEED13 = 55325248;
    int full13 = (ws_size >= NEED13) ? 1 : 0;

    prep_kernel<<<2048, 256, 0, stream>>>(pwin_w, pwout_w, dw_w, w1t, w2t, tbl, zp, full13);
    router_sum<<<320, 256, 0, stream>>>(x, pmean2, xbf, full13);
    router_top<<<NPAT, 64, 0, stream>>>(pmean2, router_w, router_b, sel_idx, sel_w);
    if (full13) {
        moe_v13<<<1600, 256, 0, stream>>>(x, ln_g, ln_b, pwin_b, pwout_b,
                                          w1t, w2t, tbl, xbf, (const unsigned short*)zp,
                                          sel_idx, sel_w, out);
    } else {
        moe_v12<<<1600, 256, 0, stream>>>(x, ln_g, ln_b, pwin_b, pwout_b,
                                          w1t, w2t, tbl, sel_idx, sel_w, out);
    }
}

// Round 14
// 199.020 us; speedup vs baseline: 1.8919x; 1.8919x over previous
//
#include <hip/hip_runtime.h>

#define NB 2
#define CCH 64
#define LL 8
#define HH 160
#define WW 160
#define PP 8
#define NPH 20
#define NPW 20
#define NPAT 800
#define NE 8
#define HWX 25600
#define CSTRIDE 204800

typedef float f32x4  __attribute__((ext_vector_type(4)));
typedef float f32x16 __attribute__((ext_vector_type(16)));
typedef short bf16x8 __attribute__((ext_vector_type(8)));

__device__ __host__ __forceinline__ unsigned short f2bf(float f) {
    unsigned u = __builtin_bit_cast(unsigned, f);
    u = (u + 0x7FFFu + ((u >> 16) & 1u)) >> 16;
    return (unsigned short)u;
}
__device__ __forceinline__ unsigned cvtpk(float lo, float hi) {
    unsigned r;
    asm("v_cvt_pk_bf16_f32 %0, %1, %2" : "=v"(r) : "v"(lo), "v"(hi));
    return r;
}
__device__ __forceinline__ float dpp_xor1(float v) {  // quad_perm [1,0,3,2]
    int s = __builtin_bit_cast(int, v);
    return __builtin_bit_cast(float, __builtin_amdgcn_update_dpp(s, s, 0xB1, 0xF, 0xF, false));
}
__device__ __forceinline__ int xsw(int s) { return ((s & 7) ^ ((s >> 3) & 7)) << 2; }

// ---------------- Prep: w1t (interleaved a/g rows), w2t, paired block-diagonal conv table ----
__global__ __launch_bounds__(256)
void prep_kernel(const float* __restrict__ pwin_w, const float* __restrict__ pwout_w,
                 const float* __restrict__ dw_w,
                 unsigned short* __restrict__ w1t, unsigned short* __restrict__ w2t,
                 unsigned short* __restrict__ tbl, unsigned* __restrict__ zp, int full)
{
    int idx = blockIdx.x * 256 + threadIdx.x;    // grid 2048 -> 524288
    {
        int j = idx & 7, lane = (idx >> 3) & 63, ks2 = (idx >> 9) & 3;
        int po = (idx >> 11) & 31, e = (idx >> 16) & 7;
        int m16 = lane & 15;
        int ch = m16 >> 3, jout = m16 & 7;
        int k128 = ks2*32 + ((lane >> 4) << 3) + j;
        int kc = k128 >> 6, k64 = k128 & 63;
        int di = k64 >> 3, jj = k64 & 7;
        int dj = jj - jout + 3;
        int h = po >> 4, mm = po & 15;
        int c = 32*h + mm + ch*16;
        float v = 0.f;
        if (kc == ch && di < 7 && dj >= 0 && dj < 7)
            v = dw_w[(e*CCH + c)*49 + di*7 + dj];
        tbl[idx] = f2bf(v);
    }
    if (idx < NE*128*64) {
        int e = idx >> 13, r = (idx >> 6) & 127, c = idx & 63;
        int orig = (r & 1) ? 64 + (r >> 1) : (r >> 1);
        w1t[idx] = f2bf(pwin_w[(e << 13) + orig*64 + c]);
    }
    if (idx < NE*64*64) w2t[idx] = f2bf(pwout_w[idx]);
    if (full && idx < 16) zp[idx] = 0u;
}

// ---------------- Router stage 1: partial sums + (optional) xbf conversion ----------------
// xbf tile T=((b*20+ph)*10+pwq)*4+lp : [c][l2][row][p][j] bf16, 16384 ushorts/tile
__global__ __launch_bounds__(256)
void router_sum(const float* __restrict__ x, float* __restrict__ pmean2,
                unsigned short* __restrict__ xbf, int do_xbf)
{
    int bid = blockIdx.x;                        // 320 = b(2) x l(8) x ph(20)
    int ph = bid % 20;
    int r  = bid / 20;
    int l  = r % 8;
    int b  = r / 8;
    int lp = l >> 1, l2 = l & 1;

    __shared__ float acc[1280];
    const float* base = x + ((size_t)(b*CCH)*LL + l)*HWX + (size_t)(ph*PP)*WW;
    int t = threadIdx.x;

    #pragma unroll
    for (int k = 0; k < 5; ++k) {
        int s = t + 256*k;
        int pw = s % 20, c = s / 20;
        const float* rp = base + (size_t)c*CSTRIDE + pw*8;
        int pwq = pw >> 1, pp2 = pw & 1;
        size_t tb = ((((size_t)(b*20 + ph))*10 + pwq)*4 + lp)*16384
                    + (size_t)c*256 + l2*128 + pp2*8;
        float sum = 0.f;
        #pragma unroll
        for (int i = 0; i < 8; ++i) {
            float4 v0 = *(const float4*)(rp + i*WW);
            float4 v1 = *(const float4*)(rp + i*WW + 4);
            sum += v0.x+v0.y+v0.z+v0.w + v1.x+v1.y+v1.z+v1.w;
            if (do_xbf) {
                uint4 wv;
                wv.x = cvtpk(v0.x, v0.y);
                wv.y = cvtpk(v0.z, v0.w);
                wv.z = cvtpk(v1.x, v1.y);
                wv.w = cvtpk(v1.z, v1.w);
                *(uint4*)(xbf + tb + i*16) = wv;
            }
        }
        acc[c*20 + pw] = sum;
    }
    __syncthreads();
    #pragma unroll
    for (int k = 0; k < 5; ++k) {
        int s = t + 256*k;
        int c = s & 63, pwi = s >> 6;
        int n = b*400 + ph*20 + pwi;
        pmean2[(size_t)n*512 + l*64 + c] = acc[c*20 + pwi];
    }
}

// ---------------- Router stage 2: logits + top-2 softmax ----------------
__global__ __launch_bounds__(64)
void router_top(const float* __restrict__ pmean2,
                const float* __restrict__ rw, const float* __restrict__ rb,
                int* __restrict__ sel_idx, float* __restrict__ sel_w)
{
    int n = blockIdx.x;
    int t = threadIdx.x;
    __shared__ float mc[64];
    __shared__ float lg[8];
    const float* pb = pmean2 + (size_t)n*512;
    float s = 0.f;
    #pragma unroll
    for (int l = 0; l < 8; ++l) s += pb[l*64 + t];
    mc[t] = s * (1.f/512.f);
    __syncthreads();
    if (t < 8) {
        float a = rb[t];
        for (int c = 0; c < 64; ++c) a += mc[c] * rw[t*64 + c];
        lg[t] = a;
    }
    __syncthreads();
    if (t == 0) {
        float m0 = -1e30f; int i0 = 0;
        #pragma unroll
        for (int e = 0; e < NE; ++e) { float v = lg[e]; if (v > m0) { m0 = v; i0 = e; } }
        float m1 = -1e30f; int i1 = 0;
        #pragma unroll
        for (int e = 0; e < NE; ++e) { if (e != i0) { float v = lg[e]; if (v > m1) { m1 = v; i1 = e; } } }
        float dd = __expf(m1 - m0);
        float inv = 1.f / (1.f + dd);
        sel_idx[n*2]   = i0;  sel_idx[n*2+1] = i1;
        sel_w[n*2]     = inv; sel_w[n*2+1]   = dd * inv;
    }
}

// ---------------- Main v14: v13 with (256,2) bounds — no AGPR spill, LDS-driven occupancy ----
__global__ __launch_bounds__(256, 2)
void moe_v14(const float* __restrict__ x,
             const float* __restrict__ ln_g,
             const float* __restrict__ ln_b,
             const float* __restrict__ pwin_b,
             const float* __restrict__ pwout_b,
             const unsigned short* __restrict__ w1t,
             const unsigned short* __restrict__ w2t,
             const unsigned short* __restrict__ tbl,
             const unsigned short* __restrict__ xbf,
             const unsigned short* __restrict__ zp,
             const int* __restrict__ sel_idx,
             const float* __restrict__ sel_w,
             float* __restrict__ out)
{
    __shared__ __align__(16) unsigned smem[8224];    // 4 slices x 2056 dwords (~32 KB)
    float* obuf = (float*)smem;                      // epilogue reuse [0,8192)

    int bid = blockIdx.x;
    int xg = bid & 7, pp = (bid >> 3) & 1, w = bid >> 4;
    int b = xg >> 2, lp = xg & 3;
    int ph = w / 5, pwh = w - ph*5;
    int pwq = pwh*2 + pp;

    int t = threadIdx.x;
    int lane = t & 63;
    int wv = __builtin_amdgcn_readfirstlane(t >> 6);
    int p = wv & 1;
    int h = wv >> 1;
    int col16 = lane & 15, grp = lane >> 4;
    int io = col16 & 7, l2n = col16 >> 3;
    int laneM = lane & 31, hi = lane >> 5;
    bool oddl = (lane & 1) != 0;
    int srow_b = (oddl ? 32 : 0) + 4*hi;
    int sx = (h & 1) << 2;

    size_t xpb = ((size_t)(b*CCH)*LL + lp*2)*HWX + (size_t)(ph*PP)*WW + pwq*16;
    int np = b*400 + ph*20 + pwq*2 + p;
    int Tidx = ((b*20 + ph)*10 + pwq)*4 + lp;
    const unsigned short* xt = xbf + (size_t)Tidx*16384;

    int e0 = __builtin_amdgcn_readfirstlane(sel_idx[np*2]);
    int e1 = __builtin_amdgcn_readfirstlane(sel_idx[np*2+1]);
    float wA = sel_w[np*2], wB = sel_w[np*2+1];

    f32x16 oacc[2][2];
    #pragma unroll
    for (int st = 0; st < 2; ++st)
        #pragma unroll
        for (int ct = 0; ct < 2; ++ct)
            #pragma unroll
            for (int i = 0; i < 16; ++i) oacc[st][ct][i] = 0.f;

    unsigned* sl = smem + (p*2 + h)*2056;

    int loff[2]; bool okr[2];
    #pragma unroll
    for (int ks = 0; ks < 2; ++ks) {
        int row = io + ks*4 + grp - 3;
        loff[ks] = l2n*128 + (row & 7)*16 + p*8;
        okr[ks] = (unsigned)row < 8u;
    }
    int sb = io*8 + (grp & 1)*4;
    int chs = grp >> 1;
    int sp2 = p*2 + l2n;
    int csx = l2n << 2;

    #pragma unroll 1
    for (int pass = 0; pass < 2; ++pass) {
        int e    = pass ? e1 : e0;
        float we = pass ? wB : wA;

        // ---- conv: paired block-diagonal MFMA (B from global xbf) + per-channel LN ----
        const unsigned short* te = tbl + (((size_t)(e*32 + h*16)) << 11);
        float gv[4], bv[4];
        #pragma unroll
        for (int r = 0; r < 4; ++r) {
            gv[r] = ln_g[e*64 + sb + r];
            bv[r] = ln_b[e*64 + sb + r];
        }

        #pragma unroll 2
        for (int m = 0; m < 16; ++m) {
            int cA = 32*h + m;
            const unsigned short* tm = te + ((size_t)m << 11);
            f32x4 ac; ac[0]=0.f; ac[1]=0.f; ac[2]=0.f; ac[3]=0.f;
            #pragma unroll
            for (int ks2 = 0; ks2 < 4; ++ks2) {
                int cc = cA + ((ks2 & 2) ? 16 : 0);
                int ks = ks2 & 1;
                const unsigned short* bp = okr[ks] ? (xt + cc*256 + loff[ks]) : zp;
                uint4 bu = *(const uint4*)bp;
                uint4 af = *(const uint4*)(tm + ks2*512 + lane*8);
                ac = __builtin_amdgcn_mfma_f32_16x16x32_bf16(
                    __builtin_bit_cast(bf16x8, af), __builtin_bit_cast(bf16x8, bu), ac, 0, 0, 0);
            }
            float sum = ac[0]+ac[1]+ac[2]+ac[3];
            float sq  = 0.f;
            #pragma unroll
            for (int r = 0; r < 4; ++r) sq = fmaf(ac[r], ac[r], sq);
            sum += __shfl_xor(sum, 1);  sq += __shfl_xor(sq, 1);
            sum += __shfl_xor(sum, 2);  sq += __shfl_xor(sq, 2);
            sum += __shfl_xor(sum, 4);  sq += __shfl_xor(sq, 4);
            sum += __shfl_xor(sum, 16); sq += __shfl_xor(sq, 16);
            float mu  = sum * 0.015625f;
            float var = fmaxf(fmaf(sq, 0.015625f, -mu*mu), 0.f);
            float inv = rsqrtf(var + 1e-5f);
            float nmu = -mu * inv;
            int myc = cA + (chs ? 16 : 0);
            unsigned short* Yh = (unsigned short*)smem;
            int cd = (myc >> 1), cb = myc & 1;
            #pragma unroll
            for (int r = 0; r < 4; ++r) {
                float y = fmaf(fmaf(ac[r], inv, nmu), gv[r], bv[r]);
                int s = sb + r;
                int dw = sp2*2056 + s*32 + ((cd ^ xsw(s)) ^ csx);
                Yh[dw*2 + cb] = (unsigned short)cvtpk(y, y);
            }
        }
        __syncthreads();                             // B2: all Y slices complete

        // ---- solo GEMMs on private slice ----
        uint4 aY0[4], aY1[4];
        #pragma unroll
        for (int ks = 0; ks < 4; ++ks) {
            int kd = 8*ks + 4*hi;
            aY0[ks] = *(const uint4*)&sl[laneM*32 + ((kd ^ xsw(laneM)) ^ sx)];
            aY1[ks] = *(const uint4*)&sl[(32 + laneM)*32 + ((kd ^ xsw(32 + laneM)) ^ sx)];
        }
        const unsigned short* w1e = w1t + ((size_t)e << 13);
        const unsigned short* w2e = w2t + ((size_t)e << 12);

        #pragma unroll 1
        for (int dt = 0; dt < 4; ++dt) {
            uint4 b1f[4];
            #pragma unroll
            for (int ks = 0; ks < 4; ++ks)
                b1f[ks] = *(const uint4*)(w1e + (32*dt + laneM)*64 + 16*ks + 8*hi);
            int dp = 32*dt + laneM;
            int borig = (dp & 1) ? 64 + (dp >> 1) : (dp >> 1);
            float bias1 = pwin_b[e*128 + borig];

            f32x16 acc0, acc1;
            #pragma unroll
            for (int i = 0; i < 16; ++i) { acc0[i]=0.f; acc1[i]=0.f; }
            #pragma unroll
            for (int ks = 0; ks < 4; ++ks) {
                bf16x8 bvf = __builtin_bit_cast(bf16x8, b1f[ks]);
                acc0 = __builtin_amdgcn_mfma_f32_32x32x16_bf16(
                    __builtin_bit_cast(bf16x8, aY0[ks]), bvf, acc0, 0, 0, 0);
                acc1 = __builtin_amdgcn_mfma_f32_32x32x16_bf16(
                    __builtin_bit_cast(bf16x8, aY1[ks]), bvf, acc1, 0, 0, 0);
            }
            int kg  = 16*dt + (laneM >> 1);
            int kdg = kg >> 1, kbit = kg & 1;
            #pragma unroll
            for (int r = 0; r < 16; ++r) {
                float h0 = acc0[r] + bias1;
                float h1 = acc1[r] + bias1;
                float p0 = dpp_xor1(h0);
                float p1 = dpp_xor1(h1);
                float A = oddl ? p1 : h0;
                float G = oddl ? h1 : p0;
                float sg = __builtin_amdgcn_rcpf(1.f + __expf(-A));
                float val = A * sg * G;
                int srow = srow_b + (r & 3) + 8*(r >> 2);
                int dwg = srow*32 + ((kdg ^ xsw(srow)) ^ sx);
                ((unsigned short*)sl)[dwg*2 + kbit] = (unsigned short)cvtpk(val, val);
            }
        }
        // ---- GEMM2 ----
        #pragma unroll
        for (int ct = 0; ct < 2; ++ct) {
            int cn = 32*ct + laneM;
            uint4 b2f[4];
            #pragma unroll
            for (int ks = 0; ks < 4; ++ks)
                b2f[ks] = *(const uint4*)(w2e + cn*64 + 16*ks + 8*hi);
            float bias2 = pwout_b[e*64 + cn];
            #pragma unroll
            for (int st = 0; st < 2; ++st) {
                f32x16 g;
                #pragma unroll
                for (int i = 0; i < 16; ++i) g[i] = 0.f;
                #pragma unroll
                for (int ks = 0; ks < 4; ++ks) {
                    int sG = 32*st + laneM;
                    int kd = 8*ks + 4*hi;
                    uint4 ag = *(const uint4*)&sl[sG*32 + ((kd ^ xsw(sG)) ^ sx)];
                    g = __builtin_amdgcn_mfma_f32_32x32x16_bf16(
                        __builtin_bit_cast(bf16x8, ag), __builtin_bit_cast(bf16x8, b2f[ks]), g, 0, 0, 0);
                }
                #pragma unroll
                for (int i = 0; i < 16; ++i)
                    oacc[st][ct][i] = fmaf(we, g[i] + bias2, oacc[st][ct][i]);
            }
        }
        __syncthreads();                             // B3: slice reads done
    }

    // ---- epilogue: 2 phases (l2 = 0,1), 32 KB obuf per phase, float4 global I/O ----
    #pragma unroll 1
    for (int ph2 = 0; ph2 < 2; ++ph2) {
        if (h == ph2) {
            float* obr = obuf + p*4096;
            #pragma unroll
            for (int st = 0; st < 2; ++st)
                #pragma unroll
                for (int ct = 0; ct < 2; ++ct)
                    #pragma unroll
                    for (int r = 0; r < 16; ++r) {
                        int c = 32*ct + laneM;
                        int s = 32*st + 4*hi + (r & 3) + 8*(r >> 2);
                        obr[c*64 + (s ^ c)] = oacc[st][ct][r];
                    }
        }
        __syncthreads();
        #pragma unroll
        for (int rr = 0; rr < 8; ++rr) {
            int row = rr*64 + (t >> 2);              // 0..511 = (c, i)
            int c = row >> 3, i = row & 7;
            int q4 = (t & 3) * 4;
            int pq = q4 >> 3;
            int jb = q4 & 7;
            int ob = pq*4096 + c*64;
            float4 v;
            v.x = obuf[ob + ((i*8 + jb + 0) ^ c)];
            v.y = obuf[ob + ((i*8 + jb + 1) ^ c)];
            v.z = obuf[ob + ((i*8 + jb + 2) ^ c)];
            v.w = obuf[ob + ((i*8 + jb + 3) ^ c)];
            size_t ga = xpb + (size_t)c*CSTRIDE + (size_t)ph2*HWX + i*WW + q4;
            float4 xr = *(const float4*)(x + ga);
            v.x += xr.x; v.y += xr.y; v.z += xr.z; v.w += xr.w;
            *(float4*)(out + ga) = v;
        }
        if (ph2 == 0) __syncthreads();
    }
}

// ---------------- Fallback: verified v12 kernel (LDS xs staging) ----------------
__global__ __launch_bounds__(256, 2)
void moe_v12(const float* __restrict__ x,
             const float* __restrict__ ln_g,
             const float* __restrict__ ln_b,
             const float* __restrict__ pwin_b,
             const float* __restrict__ pwout_b,
             const unsigned short* __restrict__ w1t,
             const unsigned short* __restrict__ w2t,
             const unsigned short* __restrict__ tbl,
             const int* __restrict__ sel_idx,
             const float* __restrict__ sel_w,
             float* __restrict__ out)
{
    __shared__ __align__(16) unsigned smem[16400];
    unsigned* xs = smem;
    float* obuf  = (float*)smem;

    int bid = blockIdx.x;
    int xg = bid & 7, pp = (bid >> 3) & 1, w = bid >> 4;
    int b = xg >> 2, lp = xg & 3;
    int ph = w / 5, pwh = w - ph*5;
    int pwq = pwh*2 + pp;

    int t = threadIdx.x;
    int lane = t & 63;
    int wv = __builtin_amdgcn_readfirstlane(t >> 6);
    int p = wv & 1;
    int h = wv >> 1;
    int col16 = lane & 15, grp = lane >> 4;
    int io = col16 & 7, l2n = col16 >> 3;
    int laneM = lane & 31, hi = lane >> 5;
    bool oddl = (lane & 1) != 0;
    int srow_b = (oddl ? 32 : 0) + 4*hi;
    int sx = (h & 1) << 2;

    size_t xpb = ((size_t)(b*CCH)*LL + lp*2)*HWX + (size_t)(ph*PP)*WW + pwq*16;
    int np = b*400 + ph*20 + pwq*2 + p;

    if (t < 16) smem[16384 + t] = 0u;

    #pragma unroll
    for (int k = 0; k < 16; ++k) {
        int id = t + 256*k;
        int part = id & 3, i = (id >> 2) & 7, l2s = (id >> 5) & 1, c = id >> 6;
        const float* rp = x + xpb + (size_t)c*CSTRIDE + (size_t)l2s*HWX + i*WW + part*4;
        float4 v = *(const float4*)rp;
        uint2 bu;
        bu.x = cvtpk(v.x, v.y);
        bu.y = cvtpk(v.z, v.w);
        int off = (part*2) ^ (((l2s ^ (i >> 2)) & 1) << 2);
        *(uint2*)&xs[c*128 + l2s*64 + i*8 + off] = bu;
    }
    __syncthreads();

    int e0 = __builtin_amdgcn_readfirstlane(sel_idx[np*2]);
    int e1 = __builtin_amdgcn_readfirstlane(sel_idx[np*2+1]);
    float wA = sel_w[np*2], wB = sel_w[np*2+1];

    f32x16 oacc[2][2];
    #pragma unroll
    for (int st = 0; st < 2; ++st)
        #pragma unroll
        for (int ct = 0; ct < 2; ++ct)
            #pragma unroll
            for (int i = 0; i < 16; ++i) oacc[st][ct][i] = 0.f;

    unsigned* sl = smem + 8192 + (p*2 + h)*2048;

    int rowoff[2]; bool okr[2];
    #pragma unroll
    for (int ks = 0; ks < 2; ++ks) {
        int row = io + ks*4 + grp - 3;
        int rw = row & 7;
        rowoff[ks] = l2n*64 + rw*8 + (((p ^ l2n ^ (rw >> 2)) & 1) << 2);
        okr[ks] = (unsigned)row < 8u;
    }
    int sb = io*8 + (grp & 1)*4;
    int chs = grp >> 1;
    int sp2 = p*2 + l2n;
    int csx = l2n << 2;

    #pragma unroll 1
    for (int pass = 0; pass < 2; ++pass) {
        int e    = pass ? e1 : e0;
        float we = pass ? wB : wA;

        const unsigned short* te = tbl + (((size_t)(e*32 + h*16)) << 11);
        float gv[4], bv[4];
        #pragma unroll
        for (int r = 0; r < 4; ++r) {
            gv[r] = ln_g[e*64 + sb + r];
            bv[r] = ln_b[e*64 + sb + r];
        }

        #pragma unroll 2
        for (int m = 0; m < 16; ++m) {
            int cA = 32*h + m;
            const unsigned short* tm = te + ((size_t)m << 11);
            f32x4 ac; ac[0]=0.f; ac[1]=0.f; ac[2]=0.f; ac[3]=0.f;
            #pragma unroll
            for (int ks2 = 0; ks2 < 4; ++ks2) {
                int c = cA + ((ks2 & 2) ? 16 : 0);
                int ks = ks2 & 1;
                int aB = okr[ks] ? (c*128 + rowoff[ks]) : 16384;
                uint4 bu = *(const uint4*)&xs[aB];
                uint4 af = *(const uint4*)(tm + ks2*512 + lane*8);
                ac = __builtin_amdgcn_mfma_f32_16x16x32_bf16(
                    __builtin_bit_cast(bf16x8, af), __builtin_bit_cast(bf16x8, bu), ac, 0, 0, 0);
            }
            float sum = ac[0]+ac[1]+ac[2]+ac[3];
            float sq  = 0.f;
            #pragma unroll
            for (int r = 0; r < 4; ++r) sq = fmaf(ac[r], ac[r], sq);
            sum += __shfl_xor(sum, 1);  sq += __shfl_xor(sq, 1);
            sum += __shfl_xor(sum, 2);  sq += __shfl_xor(sq, 2);
            sum += __shfl_xor(sum, 4);  sq += __shfl_xor(sq, 4);
            sum += __shfl_xor(sum, 16); sq += __shfl_xor(sq, 16);
            float mu  = sum * 0.015625f;
            float var = fmaxf(fmaf(sq, 0.015625f, -mu*mu), 0.f);
            float inv = rsqrtf(var + 1e-5f);
            float nmu = -mu * inv;
            int myc = cA + (chs ? 16 : 0);
            unsigned short* Yh = (unsigned short*)smem;
            int cd = (myc >> 1), cb = myc & 1;
            #pragma unroll
            for (int r = 0; r < 4; ++r) {
                float y = fmaf(fmaf(ac[r], inv, nmu), gv[r], bv[r]);
                int s = sb + r;
                int dw = 8192 + sp2*2048 + s*32 + ((cd ^ xsw(s)) ^ csx);
                Yh[dw*2 + cb] = (unsigned short)cvtpk(y, y);
            }
        }
        __syncthreads();

        uint4 aY0[4], aY1[4];
        #pragma unroll
        for (int ks = 0; ks < 4; ++ks) {
            int kd = 8*ks + 4*hi;
            aY0[ks] = *(const uint4*)&sl[laneM*32 + ((kd ^ xsw(laneM)) ^ sx)];
            aY1[ks] = *(const uint4*)&sl[(32 + laneM)*32 + ((kd ^ xsw(32 + laneM)) ^ sx)];
        }
        const unsigned short* w1e = w1t + ((size_t)e << 13);
        const unsigned short* w2e = w2t + ((size_t)e << 12);

        #pragma unroll 1
        for (int dt = 0; dt < 4; ++dt) {
            uint4 b1f[4];
            #pragma unroll
            for (int ks = 0; ks < 4; ++ks)
                b1f[ks] = *(const uint4*)(w1e + (32*dt + laneM)*64 + 16*ks + 8*hi);
            int dp = 32*dt + laneM;
            int borig = (dp & 1) ? 64 + (dp >> 1) : (dp >> 1);
            float bias1 = pwin_b[e*128 + borig];

            f32x16 acc0, acc1;
            #pragma unroll
            for (int i = 0; i < 16; ++i) { acc0[i]=0.f; acc1[i]=0.f; }
            #pragma unroll
            for (int ks = 0; ks < 4; ++ks) {
                bf16x8 bvf = __builtin_bit_cast(bf16x8, b1f[ks]);
                acc0 = __builtin_amdgcn_mfma_f32_32x32x16_bf16(
                    __builtin_bit_cast(bf16x8, aY0[ks]), bvf, acc0, 0, 0, 0);
                acc1 = __builtin_amdgcn_mfma_f32_32x32x16_bf16(
                    __builtin_bit_cast(bf16x8, aY1[ks]), bvf, acc1, 0, 0, 0);
            }
            int kg  = 16*dt + (laneM >> 1);
            int kdg = kg >> 1, kbit = kg & 1;
            #pragma unroll
            for (int r = 0; r < 16; ++r) {
                float h0 = acc0[r] + bias1;
                float h1 = acc1[r] + bias1;
                float p0 = dpp_xor1(h0);
                float p1 = dpp_xor1(h1);
                float A = oddl ? p1 : h0;
                float G = oddl ? h1 : p0;
                float sg = __builtin_amdgcn_rcpf(1.f + __expf(-A));
                float val = A * sg * G;
                int srow = srow_b + (r & 3) + 8*(r >> 2);
                int dwg = srow*32 + ((kdg ^ xsw(srow)) ^ sx);
                ((unsigned short*)sl)[dwg*2 + kbit] = (unsigned short)cvtpk(val, val);
            }
        }
        #pragma unroll
        for (int ct = 0; ct < 2; ++ct) {
            int cn = 32*ct + laneM;
            uint4 b2f[4];
            #pragma unroll
            for (int ks = 0; ks < 4; ++ks)
                b2f[ks] = *(const uint4*)(w2e + cn*64 + 16*ks + 8*hi);
            float bias2 = pwout_b[e*64 + cn];
            #pragma unroll
            for (int st = 0; st < 2; ++st) {
                f32x16 g;
                #pragma unroll
                for (int i = 0; i < 16; ++i) g[i] = 0.f;
                #pragma unroll
                for (int ks = 0; ks < 4; ++ks) {
                    int sG = 32*st + laneM;
                    int kd = 8*ks + 4*hi;
                    uint4 ag = *(const uint4*)&sl[sG*32 + ((kd ^ xsw(sG)) ^ sx)];
                    g = __builtin_amdgcn_mfma_f32_32x32x16_bf16(
                        __builtin_bit_cast(bf16x8, ag), __builtin_bit_cast(bf16x8, b2f[ks]), g, 0, 0, 0);
                }
                #pragma unroll
                for (int i = 0; i < 16; ++i)
                    oacc[st][ct][i] = fmaf(we, g[i] + bias2, oacc[st][ct][i]);
            }
        }
        __syncthreads();
    }

    {
        float* obr = obuf + (p*2 + h)*4096;
        #pragma unroll
        for (int st = 0; st < 2; ++st)
            #pragma unroll
            for (int ct = 0; ct < 2; ++ct)
                #pragma unroll
                for (int r = 0; r < 16; ++r) {
                    int c = 32*ct + laneM;
                    int s = 32*st + 4*hi + (r & 3) + 8*(r >> 2);
                    obr[c*64 + (s ^ c)] = oacc[st][ct][r];
                }
        __syncthreads();
        #pragma unroll
        for (int rr = 0; rr < 16; ++rr) {
            int row = rr*64 + (t >> 2);
            int l2s = row >> 9;
            int rem = row & 511;
            int c = rem >> 3, i = rem & 7;
            int q4 = (t & 3) * 4;
            int pq = q4 >> 3;
            int jb = q4 & 7;
            int ob = (pq*2 + l2s)*4096 + c*64;
            float4 v;
            v.x = obuf[ob + ((i*8 + jb + 0) ^ c)];
            v.y = obuf[ob + ((i*8 + jb + 1) ^ c)];
            v.z = obuf[ob + ((i*8 + jb + 2) ^ c)];
            v.w = obuf[ob + ((i*8 + jb + 3) ^ c)];
            size_t ga = xpb + (size_t)c*CSTRIDE + (size_t)l2s*HWX + i*WW + q4;
            float4 xr = *(const float4*)(x + ga);
            v.x += xr.x; v.y += xr.y; v.z += xr.z; v.w += xr.w;
            *(float4*)(out + ga) = v;
        }
    }
}

extern "C" void kernel_launch(void* const* d_in, const int* in_sizes, int n_in,
                              void* d_out, int out_size, void* d_ws, size_t ws_size,
                              hipStream_t stream) {
    const float* x        = (const float*)d_in[0];
    const float* router_w = (const float*)d_in[1];
    const float* router_b = (const float*)d_in[2];
    const float* dw_w     = (const float*)d_in[3];
    const float* ln_g     = (const float*)d_in[5];
    const float* ln_b     = (const float*)d_in[6];
    const float* pwin_w   = (const float*)d_in[7];
    const float* pwin_b   = (const float*)d_in[8];
    const float* pwout_w  = (const float*)d_in[9];
    const float* pwout_b  = (const float*)d_in[10];
    float* out = (float*)d_out;

    char* ws = (char*)d_ws;
    int*            sel_idx = (int*)ws;                        // [0, 6400)
    float*          sel_w   = (float*)(ws + 6400);             // [6400, 12800)
    unsigned short* w1t     = (unsigned short*)(ws + 12800);   // 131072 B
    unsigned short* w2t     = (unsigned short*)(ws + 143872);  // 65536 B
    unsigned short* tbl     = (unsigned short*)(ws + 209408);  // 1048576 B -> 1257984
    float*          pmean2  = (float*)(ws + 1257984);          // 1638400 B -> 2896384
    unsigned*       zp      = (unsigned*)(ws + 2896384);       // 64 B -> 2896448
    unsigned short* xbf     = (unsigned short*)(ws + 2896448); // 52428800 B -> 55325248

    const size_t NEED14 = 55325248;
    int full14 = (ws_size >= NEED14) ? 1 : 0;

    prep_kernel<<<2048, 256, 0, stream>>>(pwin_w, pwout_w, dw_w, w1t, w2t, tbl, zp, full14);
    router_sum<<<320, 256, 0, stream>>>(x, pmean2, xbf, full14);
    router_top<<<NPAT, 64, 0, stream>>>(pmean2, router_w, router_b, sel_idx, sel_w);
    if (full14) {
        moe_v14<<<1600, 256, 0, stream>>>(x, ln_g, ln_b, pwin_b, pwout_b,
                                          w1t, w2t, tbl, xbf, (const unsigned short*)zp,
                                          sel_idx, sel_w, out);
    } else {
        moe_v12<<<1600, 256, 0, stream>>>(x, ln_g, ln_b, pwin_b, pwout_b,
                                          w1t, w2t, tbl, sel_idx, sel_w, out);
    }
}